// Round 6
// baseline (1277.921 us; speedup 1.0000x reference)
//
#include <hip/hip_runtime.h>
#include <math.h>

#define NM 50000
#define ND 50000
#define NN 100000   // total nodes
#define DK 256      // feature dim of both sims
#define F  64       // attn feature size
#define SLOPE 0.2f

// proj tiling: 128 rows x 64 cols per block, BK=32, 8x8 micro-tile, 128 threads
#define BRP  128
#define BKP  32
#define NBP  391    // ceil(50000/128)

__device__ __forceinline__ void gload_lds16(const void* g, void* l) {
    __builtin_amdgcn_global_load_lds((const __attribute__((address_space(1))) void*)g,
                                     (__attribute__((address_space(3))) void*)l, 16, 0, 0);
}

// ---------------- projection: z = [m_sim @ Wm^T ; d_sim @ Wd^T] ----------------
// 8x8 micro-tile halves LDS-read volume vs 4x4 (1.64 GB total -> ~31 us floor).
// Staging via global_load_lds (width 16): zero prefetch VGPRs (R5's spill driver).
// LDS linear [row][32 floats]; XOR swizzle (col16 ^= row&7) applied to the GLOBAL
// source on stage and to the READ address (same involution, rule both-sides).
// a-reads: 8 distinct rows -> slot k4^ty distinct per ty -> conflict-free bcast.
// w-reads: slot k4^tx distinct -> conflict-free.
__global__ __launch_bounds__(128, 2) void proj_kernel(const float* __restrict__ m_sim,
                                                      const float* __restrict__ d_sim,
                                                      const float* __restrict__ Wm,
                                                      const float* __restrict__ Wd,
                                                      float* __restrict__ z) {
    __shared__ float As[BRP * BKP];  // 16 KB, row stride 128 B
    __shared__ float Ws[F * BKP];    //  8 KB

    int bid  = blockIdx.x;
    bool ism = bid < NBP;
    const float* sim = ism ? m_sim : d_sim;
    const float* W   = ism ? Wm : Wd;
    int row0   = (ism ? bid : bid - NBP) * BRP;
    int nrows  = ism ? NM : ND;
    int zbase  = ism ? 0 : NM;

    int t  = threadIdx.x;     // 0..127
    int tx = t & 7;           // col octet 0..7
    int ty = t >> 3;          // row group 0..15
    int w  = t >> 6;          // wave 0..1
    int l  = t & 63;          // lane
    int lrow = l >> 3;        // 0..7 (row within 8-row chunk)
    int sw   = ((l & 7) ^ lrow) << 4;   // swizzled 16B slot within 128B k-chunk

    // per-lane global row bases for staging (A: 8 chunks/wave, W: 4 chunks/wave)
    const char* a_srcb[8];
    #pragma unroll
    for (int i = 0; i < 8; ++i) {
        int r  = w * 64 + i * 8 + lrow;
        int gr = row0 + r; if (gr > nrows - 1) gr = nrows - 1;
        a_srcb[i] = (const char*)sim + (size_t)gr * (DK * 4) + sw;
    }
    const char* w_srcb[4];
    #pragma unroll
    for (int i = 0; i < 4; ++i) {
        int r = w * 32 + i * 8 + lrow;
        w_srcb[i] = (const char*)W + (size_t)r * (DK * 4) + sw;
    }

    float acc[8][8];
    #pragma unroll
    for (int i = 0; i < 8; ++i)
        #pragma unroll
        for (int j = 0; j < 8; ++j) acc[i][j] = 0.f;

    const int NK = DK / BKP;   // 8
    for (int step = 0; step < NK; ++step) {
        int koff = step * (BKP * 4);   // 128 B per K-step
        __syncthreads();               // previous tile fully consumed
        #pragma unroll
        for (int i = 0; i < 8; ++i)
            gload_lds16(a_srcb[i] + koff, (char*)As + (w * 64 + i * 8) * 128);
        #pragma unroll
        for (int i = 0; i < 4; ++i)
            gload_lds16(w_srcb[i] + koff, (char*)Ws + (w * 32 + i * 8) * 128);
        __syncthreads();               // barrier drain waits vmcnt(0): tile ready

        #pragma unroll
        for (int k4 = 0; k4 < BKP / 4; ++k4) {
            float4 a[8], wv[8];
            #pragma unroll
            for (int i = 0; i < 8; ++i)
                a[i] = *(const float4*)((const char*)As + (i * 16 + ty) * 128
                                        + ((k4 ^ (ty & 7)) << 4));
            #pragma unroll
            for (int j = 0; j < 8; ++j)
                wv[j] = *(const float4*)((const char*)Ws + (j * 8 + tx) * 128
                                         + ((k4 ^ tx) << 4));
            #pragma unroll
            for (int i = 0; i < 8; ++i)
                #pragma unroll
                for (int j = 0; j < 8; ++j)
                    acc[i][j] += a[i].x * wv[j].x + a[i].y * wv[j].y
                               + a[i].z * wv[j].z + a[i].w * wv[j].w;
        }
    }

    #pragma unroll
    for (int i = 0; i < 8; ++i) {
        int r = row0 + i * 16 + ty;
        if (r < nrows) {
            float* zr = z + (size_t)(zbase + r) * F;
            #pragma unroll
            for (int j = 0; j < 8; ++j) zr[j * 8 + tx] = acc[i][j];
        }
    }
}

// ---------------- degree histogram over dst ----------------
__global__ void hist_kernel(const int* __restrict__ dst, int* __restrict__ deg, int E) {
    int k = blockIdx.x * blockDim.x + threadIdx.x;
    if (k < E) atomicAdd(&deg[dst[k]], 1);
}

// ---------------- block-level inclusive scan (1024 elems / block) ----------------
__global__ __launch_bounds__(256) void scanA(const int* __restrict__ deg,
                                             int* __restrict__ incl,   // = offs+1
                                             int* __restrict__ bsums) {
    __shared__ int sd[256];
    int tid  = threadIdx.x;
    int base = blockIdx.x * 1024 + tid * 4;
    int v[4];
    int run = 0;
    #pragma unroll
    for (int j = 0; j < 4; ++j) {
        int i = base + j;
        int x = (i < NN) ? deg[i] : 0;
        run += x;
        v[j] = run;
    }
    sd[tid] = run;
    __syncthreads();
    for (int off = 1; off < 256; off <<= 1) {
        int t = (tid >= off) ? sd[tid - off] : 0;
        __syncthreads();
        sd[tid] += t;
        __syncthreads();
    }
    int texcl = sd[tid] - run;
    #pragma unroll
    for (int j = 0; j < 4; ++j) {
        int i = base + j;
        if (i < NN) incl[i] = texcl + v[j];
    }
    if (tid == 255) bsums[blockIdx.x] = sd[255];
}

// ---------------- scan of the block sums (exclusive, in place) ----------------
__global__ void scanB(int* __restrict__ bsums, int nb) {
    __shared__ int sd[128];
    int tid = threadIdx.x;
    int x = (tid < nb) ? bsums[tid] : 0;
    sd[tid] = x;
    __syncthreads();
    for (int off = 1; off < 128; off <<= 1) {
        int t = (tid >= off) ? sd[tid - off] : 0;
        __syncthreads();
        sd[tid] += t;
        __syncthreads();
    }
    if (tid < nb) bsums[tid] = sd[tid] - x;
}

// ---------------- finalize offsets + init scatter cursors ----------------
__global__ __launch_bounds__(256) void scanC(int* __restrict__ offs,
                                             int* __restrict__ cursor,
                                             const int* __restrict__ bsums,
                                             const int* __restrict__ deg) {
    int base = blockIdx.x * 1024 + threadIdx.x * 4;
    int add  = bsums[blockIdx.x];
    #pragma unroll
    for (int j = 0; j < 4; ++j) {
        int i = base + j;
        if (i < NN) {
            int v = offs[i + 1] + add;
            offs[i + 1] = v;
            cursor[i]   = v - deg[i];
        }
    }
    if (blockIdx.x == 0 && threadIdx.x == 0) offs[0] = 0;
}

// ---------------- scatter edges into CSR by dst ----------------
__global__ void scatter_kernel(const int* __restrict__ src, const int* __restrict__ dst,
                               int* __restrict__ cursor, int* __restrict__ csr_src, int E) {
    int k = blockIdx.x * blockDim.x + threadIdx.x;
    if (k < E) {
        int d   = dst[k];
        int pos = atomicAdd(&cursor[d], 1);
        csr_src[pos] = src[k];
    }
}

// ---------------- fused per-dst-node: scores + online softmax + aggregation + elu ----------------
// Wave per node, 4 groups of 16 lanes; each group owns one edge slot, each lane
// holds a float4 of the 64 features. 8 edges per iteration (2 per group).
__global__ __launch_bounds__(256) void gat_kernel(const float* __restrict__ z,
                                                  const int* __restrict__ offs,
                                                  const int* __restrict__ csr_src,
                                                  float* __restrict__ out) {
    int tid  = threadIdx.x;
    int node = blockIdx.x * 4 + (tid >> 6);
    int lane = tid & 63;
    int g    = lane >> 4;     // edge slot 0..3
    int i    = lane & 15;     // feature quad 0..15
    int beg = offs[node];
    int end = offs[node + 1];

    float4 zd = *(const float4*)&z[(size_t)node * F + i * 4];

    float  m = -1e30f, ssum = 0.f;
    float4 h = {0.f, 0.f, 0.f, 0.f};

    for (int j = beg; j < end; j += 8) {
        int j0 = j + g, j1 = j + 4 + g;
        bool v0 = j0 < end, v1 = j1 < end;
        int s0 = csr_src[v0 ? j0 : beg];
        int s1 = csr_src[v1 ? j1 : beg];
        float4 a = *(const float4*)&z[(size_t)s0 * F + i * 4];
        float4 b = *(const float4*)&z[(size_t)s1 * F + i * 4];
        float p0 = a.x * zd.x + a.y * zd.y + a.z * zd.z + a.w * zd.w;
        float p1 = b.x * zd.x + b.y * zd.y + b.z * zd.z + b.w * zd.w;
        #pragma unroll
        for (int o = 1; o < 16; o <<= 1) {       // 16-lane reduce, 2 chains interleaved
            p0 += __shfl_xor(p0, o, 64);
            p1 += __shfl_xor(p1, o, 64);
        }
        float e0 = (p0 > 0.f) ? p0 : SLOPE * p0;
        float e1 = (p1 > 0.f) ? p1 : SLOPE * p1;
        e0 = v0 ? e0 : -1e30f;
        e1 = v1 ? e1 : -1e30f;
        float nm = fmaxf(m, fmaxf(e0, e1));      // v_max3
        float sc = __expf(m - nm);
        float ex0 = v0 ? __expf(e0 - nm) : 0.f;
        float ex1 = v1 ? __expf(e1 - nm) : 0.f;
        ssum = ssum * sc + ex0 + ex1;
        h.x = h.x * sc + ex0 * a.x + ex1 * b.x;
        h.y = h.y * sc + ex0 * a.y + ex1 * b.y;
        h.z = h.z * sc + ex0 * a.z + ex1 * b.z;
        h.w = h.w * sc + ex0 * a.w + ex1 * b.w;
        m = nm;
    }

    // ---- merge the 4 per-group partials (offsets 16, 32) ----
    float M = fmaxf(m, __shfl_xor(m, 16, 64));
    M = fmaxf(M, __shfl_xor(M, 32, 64));
    float sc = __expf(m - M);
    float ss = ssum * sc;
    ss += __shfl_xor(ss, 16, 64);
    ss += __shfl_xor(ss, 32, 64);
    h.x *= sc; h.y *= sc; h.z *= sc; h.w *= sc;
    h.x += __shfl_xor(h.x, 16, 64); h.x += __shfl_xor(h.x, 32, 64);
    h.y += __shfl_xor(h.y, 16, 64); h.y += __shfl_xor(h.y, 32, 64);
    h.z += __shfl_xor(h.z, 16, 64); h.z += __shfl_xor(h.z, 32, 64);
    h.w += __shfl_xor(h.w, 16, 64); h.w += __shfl_xor(h.w, 32, 64);

    if (g == 0) {
        float rs = 1.0f / ss;
        bool has = end > beg;
        float4 o;
        o.x = has ? h.x * rs : 0.f;
        o.y = has ? h.y * rs : 0.f;
        o.z = has ? h.z * rs : 0.f;
        o.w = has ? h.w * rs : 0.f;
        o.x = (o.x > 0.f) ? o.x : (__expf(o.x) - 1.f);   // elu
        o.y = (o.y > 0.f) ? o.y : (__expf(o.y) - 1.f);
        o.z = (o.z > 0.f) ? o.z : (__expf(o.z) - 1.f);
        o.w = (o.w > 0.f) ? o.w : (__expf(o.w) - 1.f);
        *(float4*)&out[(size_t)node * F + i * 4] = o;
    }
}

extern "C" void kernel_launch(void* const* d_in, const int* in_sizes, int n_in,
                              void* d_out, int out_size, void* d_ws, size_t ws_size,
                              hipStream_t stream) {
    const float* m_sim = (const float*)d_in[0];
    const float* d_sim = (const float*)d_in[1];
    const float* Wm    = (const float*)d_in[2];
    const float* Wd    = (const float*)d_in[3];
    const int*   src   = (const int*)d_in[4];
    const int*   dst   = (const int*)d_in[5];
    int E = in_sizes[4];
    float* out = (float*)d_out;

    char* ws = (char*)d_ws;
    float* z      = (float*)ws; ws += (size_t)NN * F * 4;
    int*   deg    = (int*)ws;   ws += (size_t)NN * 4;
    int*   offs   = (int*)ws;   ws += (size_t)(NN + 1) * 4;
    int*   cursor = (int*)ws;   ws += (size_t)NN * 4;
    int*   bsums  = (int*)ws;   ws += 128 * 4;
    int*   csr    = (int*)ws;   ws += (size_t)E * 4;

    hipMemsetAsync(deg, 0, (size_t)NN * 4, stream);

    proj_kernel<<<NBP * 2, 128, 0, stream>>>(m_sim, d_sim, Wm, Wd, z);
    hist_kernel<<<(E + 255) / 256, 256, 0, stream>>>(dst, deg, E);
    int nb = (NN + 1023) / 1024;   // 98
    scanA<<<nb, 256, 0, stream>>>(deg, offs + 1, bsums);
    scanB<<<1, 128, 0, stream>>>(bsums, nb);
    scanC<<<nb, 256, 0, stream>>>(offs, cursor, bsums, deg);
    scatter_kernel<<<(E + 255) / 256, 256, 0, stream>>>(src, dst, cursor, csr, E);
    gat_kernel<<<NN / 4, 256, 0, stream>>>(z, offs, csr, out);
}

// Round 7
// 387.542 us; speedup vs baseline: 3.2975x; 3.2975x over previous
//
#include <hip/hip_runtime.h>
#include <math.h>

#define NM 50000
#define ND 50000
#define NN 100000   // total nodes
#define DK 256      // feature dim of both sims
#define F  64       // attn feature size
#define SLOPE 0.2f

// proj tiling: 128 rows x 64 cols per block, BK=32, 8x4 micro-tile, 256 threads
#define BRP  128
#define BKP  32
#define NBP  391    // ceil(50000/128)

__device__ __forceinline__ void gload_lds16(const void* g, void* l) {
    __builtin_amdgcn_global_load_lds((const __attribute__((address_space(1))) void*)g,
                                     (__attribute__((address_space(3))) void*)l, 16, 0, 0);
}

// ---------------- projection: z = [m_sim @ Wm^T ; d_sim @ Wd^T] ----------------
// 8x4 micro-tile (acc 32 + a[8] 32 + one w 4 ~ 105 VGPR natural): sized to fit
// under the register file WITHOUT the compiler's snap-and-spill (R3/R5/R6 lesson:
// cap = 256/min_waves; exceeding it spills GBs of scratch). launch_bounds(256,1)
// -> cap 256, no cliff. Staging via global_load_lds w=16 (zero data VGPRs) with
// both-sides XOR swizzle — verified correct + 0 bank conflicts in R6.
// LDS floor ~47us, FMA floor 21us, HBM 16us.
__global__ __launch_bounds__(256, 1) void proj_kernel(const float* __restrict__ m_sim,
                                                      const float* __restrict__ d_sim,
                                                      const float* __restrict__ Wm,
                                                      const float* __restrict__ Wd,
                                                      float* __restrict__ z) {
    __shared__ float As[BRP * BKP];  // 16 KB, row stride 128 B
    __shared__ float Ws[F * BKP];    //  8 KB

    int bid  = blockIdx.x;
    bool ism = bid < NBP;
    const float* sim = ism ? m_sim : d_sim;
    const float* W   = ism ? Wm : Wd;
    int row0   = (ism ? bid : bid - NBP) * BRP;
    int nrows  = ism ? NM : ND;
    int zbase  = ism ? 0 : NM;

    int t  = threadIdx.x;     // 0..255
    int tx = t & 15;          // col group 0..15
    int ty = t >> 4;          // row group 0..15
    int w  = t >> 6;          // wave 0..3
    int l  = t & 63;          // lane
    int lrow = l >> 3;        // 0..7 (row within 8-row chunk of one stage instr)
    int sw   = ((l & 7) ^ lrow) << 4;   // swizzled 16B slot within 128B k-chunk

    // per-lane global source bases (A: 4 stage instrs/wave, W: 2/wave)
    const char* a_srcb[4];
    #pragma unroll
    for (int q = 0; q < 4; ++q) {
        int r  = (w * 4 + q) * 8 + lrow;          // 0..127
        int gr = row0 + r; if (gr > nrows - 1) gr = nrows - 1;
        a_srcb[q] = (const char*)sim + (size_t)gr * (DK * 4) + sw;
    }
    const char* w_srcb[2];
    #pragma unroll
    for (int q = 0; q < 2; ++q) {
        int r = (w * 2 + q) * 8 + lrow;           // 0..63
        w_srcb[q] = (const char*)W + (size_t)r * (DK * 4) + sw;
    }

    float acc[8][4];
    #pragma unroll
    for (int i = 0; i < 8; ++i)
        #pragma unroll
        for (int j = 0; j < 4; ++j) acc[i][j] = 0.f;

    const int NK = DK / BKP;   // 8
    for (int step = 0; step < NK; ++step) {
        int koff = step * (BKP * 4);   // 128 B per K-step
        __syncthreads();               // previous tile fully consumed
        #pragma unroll
        for (int q = 0; q < 4; ++q)
            gload_lds16(a_srcb[q] + koff, (char*)As + (w * 4 + q) * 1024);
        #pragma unroll
        for (int q = 0; q < 2; ++q)
            gload_lds16(w_srcb[q] + koff, (char*)Ws + (w * 2 + q) * 1024);
        __syncthreads();               // barrier drain waits vmcnt(0): tile ready

        #pragma unroll
        for (int k4 = 0; k4 < BKP / 4; ++k4) {
            float4 a[8];
            #pragma unroll
            for (int i = 0; i < 8; ++i)
                a[i] = *(const float4*)((const char*)As + (i * 16 + ty) * 128
                                        + ((k4 ^ (ty & 7)) << 4));
            #pragma unroll
            for (int j = 0; j < 4; ++j) {
                float4 wv = *(const float4*)((const char*)Ws + (j * 16 + tx) * 128
                                             + ((k4 ^ (tx & 7)) << 4));
                #pragma unroll
                for (int i = 0; i < 8; ++i)
                    acc[i][j] += a[i].x * wv.x + a[i].y * wv.y
                               + a[i].z * wv.z + a[i].w * wv.w;
            }
        }
    }

    #pragma unroll
    for (int i = 0; i < 8; ++i) {
        int r = row0 + i * 16 + ty;
        if (r < nrows) {
            float* zr = z + (size_t)(zbase + r) * F;
            #pragma unroll
            for (int j = 0; j < 4; ++j) zr[j * 16 + tx] = acc[i][j];
        }
    }
}

// ---------------- degree histogram over dst ----------------
__global__ void hist_kernel(const int* __restrict__ dst, int* __restrict__ deg, int E) {
    int k = blockIdx.x * blockDim.x + threadIdx.x;
    if (k < E) atomicAdd(&deg[dst[k]], 1);
}

// ---------------- block-level inclusive scan (1024 elems / block) ----------------
__global__ __launch_bounds__(256) void scanA(const int* __restrict__ deg,
                                             int* __restrict__ incl,   // = offs+1
                                             int* __restrict__ bsums) {
    __shared__ int sd[256];
    int tid  = threadIdx.x;
    int base = blockIdx.x * 1024 + tid * 4;
    int v[4];
    int run = 0;
    #pragma unroll
    for (int j = 0; j < 4; ++j) {
        int i = base + j;
        int x = (i < NN) ? deg[i] : 0;
        run += x;
        v[j] = run;
    }
    sd[tid] = run;
    __syncthreads();
    for (int off = 1; off < 256; off <<= 1) {
        int t = (tid >= off) ? sd[tid - off] : 0;
        __syncthreads();
        sd[tid] += t;
        __syncthreads();
    }
    int texcl = sd[tid] - run;
    #pragma unroll
    for (int j = 0; j < 4; ++j) {
        int i = base + j;
        if (i < NN) incl[i] = texcl + v[j];
    }
    if (tid == 255) bsums[blockIdx.x] = sd[255];
}

// ---------------- scan of the block sums (exclusive, in place) ----------------
__global__ void scanB(int* __restrict__ bsums, int nb) {
    __shared__ int sd[128];
    int tid = threadIdx.x;
    int x = (tid < nb) ? bsums[tid] : 0;
    sd[tid] = x;
    __syncthreads();
    for (int off = 1; off < 128; off <<= 1) {
        int t = (tid >= off) ? sd[tid - off] : 0;
        __syncthreads();
        sd[tid] += t;
        __syncthreads();
    }
    if (tid < nb) bsums[tid] = sd[tid] - x;
}

// ---------------- finalize offsets + init scatter cursors ----------------
__global__ __launch_bounds__(256) void scanC(int* __restrict__ offs,
                                             int* __restrict__ cursor,
                                             const int* __restrict__ bsums,
                                             const int* __restrict__ deg) {
    int base = blockIdx.x * 1024 + threadIdx.x * 4;
    int add  = bsums[blockIdx.x];
    #pragma unroll
    for (int j = 0; j < 4; ++j) {
        int i = base + j;
        if (i < NN) {
            int v = offs[i + 1] + add;
            offs[i + 1] = v;
            cursor[i]   = v - deg[i];
        }
    }
    if (blockIdx.x == 0 && threadIdx.x == 0) offs[0] = 0;
}

// ---------------- scatter edges into CSR by dst ----------------
__global__ void scatter_kernel(const int* __restrict__ src, const int* __restrict__ dst,
                               int* __restrict__ cursor, int* __restrict__ csr_src, int E) {
    int k = blockIdx.x * blockDim.x + threadIdx.x;
    if (k < E) {
        int d   = dst[k];
        int pos = atomicAdd(&cursor[d], 1);
        csr_src[pos] = src[k];
    }
}

// ---------------- fused per-dst-node: scores + online softmax + aggregation + elu ----------------
// Wave per node, 4 groups of 16 lanes; each group owns one edge slot, each lane
// holds a float4 of the 64 features. 8 edges per iteration (2 per group).
__global__ __launch_bounds__(256) void gat_kernel(const float* __restrict__ z,
                                                  const int* __restrict__ offs,
                                                  const int* __restrict__ csr_src,
                                                  float* __restrict__ out) {
    int tid  = threadIdx.x;
    int node = blockIdx.x * 4 + (tid >> 6);
    int lane = tid & 63;
    int g    = lane >> 4;     // edge slot 0..3
    int i    = lane & 15;     // feature quad 0..15
    int beg = offs[node];
    int end = offs[node + 1];

    float4 zd = *(const float4*)&z[(size_t)node * F + i * 4];

    float  m = -1e30f, ssum = 0.f;
    float4 h = {0.f, 0.f, 0.f, 0.f};

    for (int j = beg; j < end; j += 8) {
        int j0 = j + g, j1 = j + 4 + g;
        bool v0 = j0 < end, v1 = j1 < end;
        int s0 = csr_src[v0 ? j0 : beg];
        int s1 = csr_src[v1 ? j1 : beg];
        float4 a = *(const float4*)&z[(size_t)s0 * F + i * 4];
        float4 b = *(const float4*)&z[(size_t)s1 * F + i * 4];
        float p0 = a.x * zd.x + a.y * zd.y + a.z * zd.z + a.w * zd.w;
        float p1 = b.x * zd.x + b.y * zd.y + b.z * zd.z + b.w * zd.w;
        #pragma unroll
        for (int o = 1; o < 16; o <<= 1) {       // 16-lane reduce, 2 chains interleaved
            p0 += __shfl_xor(p0, o, 64);
            p1 += __shfl_xor(p1, o, 64);
        }
        float e0 = (p0 > 0.f) ? p0 : SLOPE * p0;
        float e1 = (p1 > 0.f) ? p1 : SLOPE * p1;
        e0 = v0 ? e0 : -1e30f;
        e1 = v1 ? e1 : -1e30f;
        float nm = fmaxf(m, fmaxf(e0, e1));      // v_max3
        float sc = __expf(m - nm);
        float ex0 = v0 ? __expf(e0 - nm) : 0.f;
        float ex1 = v1 ? __expf(e1 - nm) : 0.f;
        ssum = ssum * sc + ex0 + ex1;
        h.x = h.x * sc + ex0 * a.x + ex1 * b.x;
        h.y = h.y * sc + ex0 * a.y + ex1 * b.y;
        h.z = h.z * sc + ex0 * a.z + ex1 * b.z;
        h.w = h.w * sc + ex0 * a.w + ex1 * b.w;
        m = nm;
    }

    // ---- merge the 4 per-group partials (offsets 16, 32) ----
    float M = fmaxf(m, __shfl_xor(m, 16, 64));
    M = fmaxf(M, __shfl_xor(M, 32, 64));
    float sc = __expf(m - M);
    float ss = ssum * sc;
    ss += __shfl_xor(ss, 16, 64);
    ss += __shfl_xor(ss, 32, 64);
    h.x *= sc; h.y *= sc; h.z *= sc; h.w *= sc;
    h.x += __shfl_xor(h.x, 16, 64); h.x += __shfl_xor(h.x, 32, 64);
    h.y += __shfl_xor(h.y, 16, 64); h.y += __shfl_xor(h.y, 32, 64);
    h.z += __shfl_xor(h.z, 16, 64); h.z += __shfl_xor(h.z, 32, 64);
    h.w += __shfl_xor(h.w, 16, 64); h.w += __shfl_xor(h.w, 32, 64);

    if (g == 0) {
        float rs = 1.0f / ss;
        bool has = end > beg;
        float4 o;
        o.x = has ? h.x * rs : 0.f;
        o.y = has ? h.y * rs : 0.f;
        o.z = has ? h.z * rs : 0.f;
        o.w = has ? h.w * rs : 0.f;
        o.x = (o.x > 0.f) ? o.x : (__expf(o.x) - 1.f);   // elu
        o.y = (o.y > 0.f) ? o.y : (__expf(o.y) - 1.f);
        o.z = (o.z > 0.f) ? o.z : (__expf(o.z) - 1.f);
        o.w = (o.w > 0.f) ? o.w : (__expf(o.w) - 1.f);
        *(float4*)&out[(size_t)node * F + i * 4] = o;
    }
}

extern "C" void kernel_launch(void* const* d_in, const int* in_sizes, int n_in,
                              void* d_out, int out_size, void* d_ws, size_t ws_size,
                              hipStream_t stream) {
    const float* m_sim = (const float*)d_in[0];
    const float* d_sim = (const float*)d_in[1];
    const float* Wm    = (const float*)d_in[2];
    const float* Wd    = (const float*)d_in[3];
    const int*   src   = (const int*)d_in[4];
    const int*   dst   = (const int*)d_in[5];
    int E = in_sizes[4];
    float* out = (float*)d_out;

    char* ws = (char*)d_ws;
    float* z      = (float*)ws; ws += (size_t)NN * F * 4;
    int*   deg    = (int*)ws;   ws += (size_t)NN * 4;
    int*   offs   = (int*)ws;   ws += (size_t)(NN + 1) * 4;
    int*   cursor = (int*)ws;   ws += (size_t)NN * 4;
    int*   bsums  = (int*)ws;   ws += 128 * 4;
    int*   csr    = (int*)ws;   ws += (size_t)E * 4;

    hipMemsetAsync(deg, 0, (size_t)NN * 4, stream);

    proj_kernel<<<NBP * 2, 256, 0, stream>>>(m_sim, d_sim, Wm, Wd, z);
    hist_kernel<<<(E + 255) / 256, 256, 0, stream>>>(dst, deg, E);
    int nb = (NN + 1023) / 1024;   // 98
    scanA<<<nb, 256, 0, stream>>>(deg, offs + 1, bsums);
    scanB<<<1, 128, 0, stream>>>(bsums, nb);
    scanC<<<nb, 256, 0, stream>>>(offs, cursor, bsums, deg);
    scatter_kernel<<<(E + 255) / 256, 256, 0, stream>>>(src, dst, cursor, csr, E);
    gat_kernel<<<NN / 4, 256, 0, stream>>>(z, offs, csr, out);
}